// Round 1
// baseline (284.824 us; speedup 1.0000x reference)
//
#include <hip/hip_runtime.h>

// Problem constants (from reference)
constexpr int Zn = 20000;
constexpr int Un = 128;
constexpr int Sn = 8;
constexpr int Pn = 64;
constexpr int ROW = Sn * Un;      // 1024 floats per (z, tensor)
constexpr int ZPB = 4;            // z rows per block
constexpr int THREADS = 128;      // 2 waves; 32 lanes per z (4 u-channels/lane)

// ---------------------------------------------------------------------------
// Prep: counting-sort paths by output segment i3; precompute LDS float offsets
// (tensor_base + idx*Un) and bit-cast coefficient. Runs every launch (ws is
// re-poisoned by the harness).
// ---------------------------------------------------------------------------
__global__ void prep_kernel(const int* __restrict__ pi,
                            const float* __restrict__ pc,
                            int4* __restrict__ table,
                            int* __restrict__ segstart) {
    if (threadIdx.x != 0 || blockIdx.x != 0) return;
    int cnt[Sn];
    for (int s = 0; s < Sn; ++s) cnt[s] = 0;
    for (int p = 0; p < Pn; ++p) cnt[pi[4 * p + 3]]++;
    int off[Sn + 1];
    off[0] = 0;
    for (int s = 0; s < Sn; ++s) off[s + 1] = off[s] + cnt[s];
    for (int s = 0; s <= Sn; ++s) segstart[s] = off[s];
    int cur[Sn];
    for (int s = 0; s < Sn; ++s) cur[s] = off[s];
    for (int p = 0; p < Pn; ++p) {
        int s3 = pi[4 * p + 3];
        int slot = cur[s3]++;
        table[slot] = make_int4(pi[4 * p + 0] * Un,            // tensor0 base 0
                                ROW + pi[4 * p + 1] * Un,      // tensor1 base
                                2 * ROW + pi[4 * p + 2] * Un,  // tensor2 base
                                __float_as_int(pc[p]));
    }
}

// ---------------------------------------------------------------------------
// Main: stage 4 z-rows x 3 tensors in LDS, gather per sorted path, accumulate
// per segment in registers, one float4 store per (segment, lane).
// ---------------------------------------------------------------------------
__global__ __launch_bounds__(THREADS) void tp_kernel(
        const float* __restrict__ x0,
        const float* __restrict__ x1,
        const float* __restrict__ x2,
        const int4* __restrict__ table,
        const int* __restrict__ segstart,
        float* __restrict__ out) {
    __shared__ __align__(16) float lds[ZPB * 3 * ROW];  // 48 KB
    const int tid = threadIdx.x;
    const int zblk = blockIdx.x * ZPB;

    // ---- Stage: 4 z x 3 tensors x 1024 floats, coalesced float4 ----
    {
        const float* srcs[3] = { x0, x1, x2 };
#pragma unroll
        for (int t = 0; t < 3; ++t) {
            const float4* src = (const float4*)(srcs[t] + (size_t)zblk * ROW);
            float4* dst = (float4*)lds;
#pragma unroll
            for (int i = 0; i < (ZPB * (ROW / 4)) / THREADS; ++i) {  // 8 iters
                int idx = i * THREADS + tid;   // 0..1023 float4 across 4 rows
                int z = idx >> 8;              // /256 float4 per row
                int r = idx & 255;
                dst[(z * 3 + t) * (ROW / 4) + r] = src[z * (ROW / 4) + r];
            }
        }
    }
    __syncthreads();

    // Segment boundaries (uniform)
    int ss[Sn + 1];
#pragma unroll
    for (int i = 0; i <= Sn; ++i) ss[i] = segstart[i];

    const int lane = tid & 63;
    const int wave = tid >> 6;
    const int zloc = wave * 2 + (lane >> 5);   // 0..3
    const int u4   = (lane & 31);              // float4 slot within 128-float row
    const float* zb = lds + zloc * (3 * ROW);
    float* orow = out + (size_t)(zblk + zloc) * ROW;

#pragma unroll
    for (int seg = 0; seg < Sn; ++seg) {
        float4 acc = make_float4(0.f, 0.f, 0.f, 0.f);
        for (int k = ss[seg]; k < ss[seg + 1]; ++k) {
            int4 e = table[k];
            const float4 a = *(const float4*)(zb + e.x + u4 * 4);
            const float4 b = *(const float4*)(zb + e.y + u4 * 4);
            const float4 c = *(const float4*)(zb + e.z + u4 * 4);
            const float w = __int_as_float(e.w);
            acc.x += a.x * b.x * c.x * w;
            acc.y += a.y * b.y * c.y * w;
            acc.z += a.z * b.z * c.z * w;
            acc.w += a.w * b.w * c.w * w;
        }
        *(float4*)(orow + seg * Un + u4 * 4) = acc;
    }
}

extern "C" void kernel_launch(void* const* d_in, const int* in_sizes, int n_in,
                              void* d_out, int out_size, void* d_ws, size_t ws_size,
                              hipStream_t stream) {
    const float* x0 = (const float*)d_in[0];
    const float* x1 = (const float*)d_in[1];
    const float* x2 = (const float*)d_in[2];
    const float* pc = (const float*)d_in[3];   // path_coefficients (P,)
    const int*   pi = (const int*)d_in[4];     // path_indices (P,4)
    float* out = (float*)d_out;

    int4* table   = (int4*)d_ws;
    int*  segstart = (int*)((char*)d_ws + Pn * sizeof(int4));

    prep_kernel<<<1, 1, 0, stream>>>(pi, pc, table, segstart);
    tp_kernel<<<Zn / ZPB, THREADS, 0, stream>>>(x0, x1, x2, table, segstart, out);
}

// Round 2
// 276.802 us; speedup vs baseline: 1.0290x; 1.0290x over previous
//
#include <hip/hip_runtime.h>

constexpr int Zn = 20000;
constexpr int Un = 128;
constexpr int Sn = 8;
constexpr int Pn = 64;
constexpr int ROW = Sn * Un;          // 1024 floats per (z, tensor)
constexpr int ZPB = 2;                // z rows per block
constexpr int THREADS = 128;          // 2 waves; waves split the 8 segments

// ---------------------------------------------------------------------------
// Prep: one wave, one lane per path. Counting-sort by i3 via ballot/popc —
// no dynamically-indexed local arrays (those go to scratch = HBM latency).
// Table entries hold LDS float offsets for layout [t][z][1024] and coef.
// ---------------------------------------------------------------------------
__global__ __launch_bounds__(64) void prep_kernel(const int* __restrict__ pi,
                                                  const float* __restrict__ pc,
                                                  int4* __restrict__ table,
                                                  int* __restrict__ segstart) {
    const int p = threadIdx.x & 63;
    const int i0 = pi[4 * p + 0];
    const int i1 = pi[4 * p + 1];
    const int i2 = pi[4 * p + 2];
    const int i3 = pi[4 * p + 3];
    const float w = pc[p];
    const unsigned long long below = (1ull << p) - 1ull;

    int base = 0, slot = 0;
#pragma unroll
    for (int s = 0; s < Sn; ++s) {
        unsigned long long m = __ballot(i3 == s);
        if (i3 == s) slot = base + __popcll(m & below);
        if (p == 0) segstart[s] = base;
        base += __popcll(m);
    }
    if (p == 0) segstart[Sn] = base;   // == 64

    table[slot] = make_int4(i0 * Un,                    // tensor0: offset 0
                            ZPB * ROW + i1 * Un,        // tensor1 block base
                            2 * ZPB * ROW + i2 * Un,    // tensor2 block base
                            __float_as_int(w));
}

// ---------------------------------------------------------------------------
// Main: stage 2 z x 3 tensors (24 KB LDS -> 6 blocks/CU x 2 waves = 12
// waves/CU). Within a wave: zloc = lane>>5, u4 = lane&31 (float4 channel).
// Wave w computes segments [4w, 4w+4) -> no cross-wave reduction.
// ---------------------------------------------------------------------------
__global__ __launch_bounds__(THREADS, 3) void tp_kernel(
        const float* __restrict__ x0,
        const float* __restrict__ x1,
        const float* __restrict__ x2,
        const int4* __restrict__ table,
        const int* __restrict__ segstart,
        float* __restrict__ out) {
    __shared__ __align__(16) float lds[3 * ZPB * ROW];   // 24 KB, [t][z][1024]
    const int tid = threadIdx.x;
    const int zblk = blockIdx.x * ZPB;

    // ---- Stage: layout [t][z][row], fully coalesced float4 ----
#pragma unroll
    for (int t = 0; t < 3; ++t) {
        const float4* src = (const float4*)(t == 0 ? x0 : (t == 1 ? x1 : x2));
        float4* dst = (float4*)lds + t * (ZPB * ROW / 4);
#pragma unroll
        for (int i = 0; i < (ZPB * ROW / 4) / THREADS; ++i) {   // 4 iters
            int local = i * THREADS + tid;       // 0..511 float4
            int z = local >> 8;                  // /256 float4 per row
            int r = local & 255;
            dst[local] = src[(size_t)(zblk + z) * (ROW / 4) + r];
        }
    }
    __syncthreads();

    int ss[Sn + 1];
#pragma unroll
    for (int i = 0; i <= Sn; ++i) ss[i] = segstart[i];

    const int lane = tid & 63;
    const int wave = tid >> 6;                   // 0,1: segment split
    const int zloc = lane >> 5;                  // 0,1
    const int u4   = lane & 31;                  // float4 slot in 128-float row
    const float* zb = lds + zloc * ROW;          // + e.{x,y,z} selects tensor/row
    float* orow = out + (size_t)(zblk + zloc) * ROW;

#pragma unroll
    for (int s = wave * (Sn / 2); s < (wave + 1) * (Sn / 2); ++s) {
        float4 acc = make_float4(0.f, 0.f, 0.f, 0.f);
        for (int k = ss[s]; k < ss[s + 1]; ++k) {
            int4 e = table[k];
            const float4 a = *(const float4*)(zb + e.x + u4 * 4);
            const float4 b = *(const float4*)(zb + e.y + u4 * 4);
            const float4 c = *(const float4*)(zb + e.z + u4 * 4);
            const float w = __int_as_float(e.w);
            acc.x += a.x * b.x * c.x * w;
            acc.y += a.y * b.y * c.y * w;
            acc.z += a.z * b.z * c.z * w;
            acc.w += a.w * b.w * c.w * w;
        }
        *(float4*)(orow + s * Un + u4 * 4) = acc;
    }
}

extern "C" void kernel_launch(void* const* d_in, const int* in_sizes, int n_in,
                              void* d_out, int out_size, void* d_ws, size_t ws_size,
                              hipStream_t stream) {
    const float* x0 = (const float*)d_in[0];
    const float* x1 = (const float*)d_in[1];
    const float* x2 = (const float*)d_in[2];
    const float* pc = (const float*)d_in[3];
    const int*   pi = (const int*)d_in[4];
    float* out = (float*)d_out;

    int4* table    = (int4*)d_ws;
    int*  segstart = (int*)((char*)d_ws + Pn * sizeof(int4));

    prep_kernel<<<1, 64, 0, stream>>>(pi, pc, table, segstart);
    tp_kernel<<<Zn / ZPB, THREADS, 0, stream>>>(x0, x1, x2, table, segstart, out);
}